// Round 18
// baseline (17.670 us; speedup 1.0000x reference)
//
#include <hip/hip_runtime.h>
#include <hip/hip_bf16.h>
#include <stdint.h>

// LogLinearCDE: out = softmax(W_out @ (y0 * prod_l flows[l]) + b_out)
// flows[l,h] = 1 + sum_c logsigs[l,c]*vf_A[c,h];  y0 = W_in@x0 + b_in
// R18: R17 structure (2 kernels, race-immune single-barrier partial) with
// f16 tail traffic: ws_pp stored f16 (128 KB) and W_out converted to f16 by
// the 16 rq==0 partial blocks (disjoint 256-col slices). Tail reads 208 KB
// instead of 416 KB. Error budget: 16 f16 roundings/h + f16 Wout -> softmax
// absmax ~5e-4, 10x under threshold.

#define LSTEPS 16384
#define HID    4096
#define CC     17
#define NLAB   10
#define COLS   256              // cols per partial block
#define NCB    (HID/COLS)       // 16
#define RQ     16               // row splits
#define RPB    (LSTEPS/RQ)      // 1024 rows per block

typedef __attribute__((ext_vector_type(8)))  _Float16 half8;
typedef __attribute__((ext_vector_type(2)))  _Float16 half2v;
typedef __attribute__((ext_vector_type(8)))  short short8;
typedef __attribute__((ext_vector_type(16))) float f32x16;

static __device__ __forceinline__ unsigned short f2h(float x) {
  _Float16 h = (_Float16)x;
  return *reinterpret_cast<unsigned short*>(&h);
}
static __device__ __forceinline__ uint32_t pk(unsigned short lo, unsigned short hi) {
  return (uint32_t)lo | ((uint32_t)hi << 16);
}
static __device__ __forceinline__ half8 frag_from_word(uint32_t w) {
  short8 s = {};
  s[0] = (short)(w & 0xffffu);
  s[1] = (short)(w >> 16);
  return __builtin_bit_cast(half8, s);
}

__global__ __launch_bounds__(512, 2) void partial_kernel(
    const float* __restrict__ logsigs, const float* __restrict__ vfA,
    const float* __restrict__ Win, const float* __restrict__ bin,
    const float* __restrict__ x0, const float* __restrict__ Wout,
    _Float16* __restrict__ ws_pp16, _Float16* __restrict__ wo16) {
  const int cb = blockIdx.x;    // 0..15 col group (256 cols)
  const int rq = blockIdx.y;    // 0..15 row split (1024 rows)
  const int tid = threadIdx.x;  // 512 threads

  __shared__ __align__(16) uint32_t sA[RPB][8];    // 32 KB  (k0-15 f16 pairs)
  __shared__ uint32_t sA4[RPB];                    //  4 KB  (k16)
  __shared__ __align__(16) uint32_t sB[2][COLS][4];//  8 KB
  __shared__ uint32_t sB4[COLS];                   //  1 KB

  // ---- stage B (tid < 256): col tid; k-loop coalesces across lanes
  if (tid < COLS) {
    const int gc = cb*COLS + tid;
    float v[CC];
    #pragma unroll
    for (int k = 0; k < CC; ++k) v[k] = vfA[(size_t)k*HID + gc];
    uint32_t w0[4], w1[4];
    #pragma unroll
    for (int j = 0; j < 4; ++j) {
      w0[j] = pk(f2h(v[2*j]),   f2h(v[2*j+1]));   // k0-7
      w1[j] = pk(f2h(v[8+2*j]), f2h(v[9+2*j]));   // k8-15
    }
    *reinterpret_cast<uint4*>(&sB[0][tid][0]) = make_uint4(w0[0],w0[1],w0[2],w0[3]);
    *reinterpret_cast<uint4*>(&sB[1][tid][0]) = make_uint4(w1[0],w1[1],w1[2],w1[3]);
    sB4[tid] = pk(f2h(v[16]), 0);
  }

  // ---- rq==0 blocks: convert this col-slice of W_out to f16 (disjoint)
  if (rq == 0 && tid < COLS) {
    const int gc = cb*COLS + tid;
    #pragma unroll
    for (int j = 0; j < NLAB; ++j)
      wo16[(size_t)j*HID + gc] = (_Float16)Wout[(size_t)j*HID + gc];
  }

  // ---- stage A: 1024 rows x 2 half-rows = 2048 tasks, 4 rounds of 512
  {
    const float* __restrict__ abase = logsigs + (size_t)rq*RPB*CC;
    #pragma unroll
    for (int rd = 0; rd < 4; ++rd) {
      const int e = rd*512 + tid;
      const int r = e >> 1, hf = e & 1;
      const float* __restrict__ row = abase + (size_t)r*CC + hf*8;
      uint32_t w[4];
      #pragma unroll
      for (int j = 0; j < 4; ++j) w[j] = pk(f2h(row[2*j]), f2h(row[2*j+1]));
      *reinterpret_cast<uint4*>(&sA[r][hf*4]) = make_uint4(w[0],w[1],w[2],w[3]);
      if (hf) sA4[r] = pk(f2h(row[8]), 0);
    }
  }
  __syncthreads();      // the ONLY barrier: LDS is read-only from here on

  const int lane = tid & 63, wv = tid >> 6;   // 8 waves
  const int cl = lane & 31, kh = lane >> 5;
  const int c = wv*32 + cl;                   // col within block

  const half8 Bm = __builtin_bit_cast(half8,
                     *reinterpret_cast<const short8*>(&sB[kh][c][0]));
  const half8 B4 = frag_from_word((kh == 0) ? sB4[c] : 0u);

  float p = 1.0f;
  #pragma unroll 4
  for (int it = 0; it < RPB/32; ++it) {       // 32 row-tiles
    const int rr = it*32 + cl;
    const half8 Am = __builtin_bit_cast(half8,
                       *reinterpret_cast<const short8*>(&sA[rr][kh*4]));
    const half8 A4 = frag_from_word((kh == 0) ? sA4[rr] : 0u);
    f32x16 a = {};
    a = __builtin_amdgcn_mfma_f32_32x32x16_f16(Am, Bm, a, 0, 0, 0);
    a = __builtin_amdgcn_mfma_f32_32x32x16_f16(A4, B4, a, 0, 0, 0);
    #pragma unroll
    for (int i = 0; i < 16; ++i) p = fmaf(a[i], p, p);   // p *= (1 + a[i])
  }
  // partner lane (^32) holds the other 16 rows of each 32-row tile
  p *= __shfl_xor(p, 32, 64);

  if (kh == 0) {
    const int gc = cb*COLS + c;
    float P = p;
    if (rq == 0) {              // fold y0 = W_in@x0 + b_in
      const float4* __restrict__ wrow =
          reinterpret_cast<const float4*>(Win + (size_t)gc*16);
      float y = bin[gc];
      #pragma unroll
      for (int q = 0; q < 4; ++q) {
        float4 w = wrow[q];
        y = fmaf(w.x, x0[4*q+0], y);
        y = fmaf(w.y, x0[4*q+1], y);
        y = fmaf(w.z, x0[4*q+2], y);
        y = fmaf(w.w, x0[4*q+3], y);
      }
      P *= y;
    }
    ws_pp16[(size_t)rq*HID + gc] = (_Float16)P;
  }
}

// tail: ONE block, 1024 threads; thread owns 4 h. Reads 128KB pp16 + 80KB wo16.
__global__ __launch_bounds__(1024) void tail_kernel(
    const _Float16* __restrict__ pp16, const _Float16* __restrict__ wo16,
    const float* __restrict__ bout, float* __restrict__ out) {
  const int tid = threadIdx.x;
  __shared__ float sred[16][NLAB];
  __shared__ float slog[NLAB];

  float p0 = 1.0f, p1 = 1.0f, p2 = 1.0f, p3 = 1.0f;
  #pragma unroll
  for (int r = 0; r < RQ; ++r) {
    const uint2 v = *reinterpret_cast<const uint2*>(&pp16[(size_t)r*HID + 4*tid]);
    const half2v a = __builtin_bit_cast(half2v, v.x);
    const half2v b = __builtin_bit_cast(half2v, v.y);
    p0 *= (float)a[0]; p1 *= (float)a[1];
    p2 *= (float)b[0]; p3 *= (float)b[1];
  }

  float acc[NLAB];
  #pragma unroll
  for (int j = 0; j < NLAB; ++j) {
    const uint2 w = *reinterpret_cast<const uint2*>(&wo16[(size_t)j*HID + 4*tid]);
    const half2v a = __builtin_bit_cast(half2v, w.x);
    const half2v b = __builtin_bit_cast(half2v, w.y);
    acc[j] = (float)a[0]*p0 + (float)a[1]*p1 + (float)b[0]*p2 + (float)b[1]*p3;
  }

  const int wv = tid >> 6, lane = tid & 63;
  #pragma unroll
  for (int j = 0; j < NLAB; ++j) {
    #pragma unroll
    for (int off = 1; off < 64; off <<= 1)
      acc[j] += __shfl_xor(acc[j], off, 64);
  }
  if (lane == 0) {
    #pragma unroll
    for (int j = 0; j < NLAB; ++j) sred[wv][j] = acc[j];
  }
  __syncthreads();
  if (tid < NLAB) {
    float s = bout[tid];
    #pragma unroll
    for (int w = 0; w < 16; ++w) s += sred[w][tid];
    slog[tid] = s;
  }
  __syncthreads();
  if (tid == 0) {
    float m = slog[0];
    #pragma unroll
    for (int j = 1; j < NLAB; ++j) m = fmaxf(m, slog[j]);
    float ssum = 0.0f;
    float e[NLAB];
    #pragma unroll
    for (int j = 0; j < NLAB; ++j) { e[j] = __expf(slog[j] - m); ssum += e[j]; }
    const float inv = 1.0f / ssum;
    #pragma unroll
    for (int j = 0; j < NLAB; ++j) out[j] = e[j] * inv;
  }
}

extern "C" void kernel_launch(void* const* d_in, const int* in_sizes, int n_in,
                              void* d_out, int out_size, void* d_ws, size_t ws_size,
                              hipStream_t stream) {
  // inputs: 0=ts (unused), 1=logsigs (L,C), 2=x0 (D), 3=W_in (H,D), 4=b_in (H),
  //         5=vf_A (C,H), 6=W_out (10,H), 7=b_out (10)
  const float* logsigs = (const float*)d_in[1];
  const float* x0      = (const float*)d_in[2];
  const float* Win     = (const float*)d_in[3];
  const float* bin     = (const float*)d_in[4];
  const float* vfA     = (const float*)d_in[5];
  const float* Wout    = (const float*)d_in[6];
  const float* bout    = (const float*)d_in[7];
  float* out = (float*)d_out;

  _Float16* ws_pp16 = (_Float16*)d_ws;                   // RQ*HID f16 = 128 KB
  _Float16* wo16    = ws_pp16 + (size_t)RQ*HID;          // 10*HID f16 = 80 KB

  partial_kernel<<<dim3(NCB, RQ), 512, 0, stream>>>(logsigs, vfA, Win, bin, x0,
                                                    Wout, ws_pp16, wo16);
  tail_kernel<<<1, 1024, 0, stream>>>(ws_pp16, wo16, bout, out);
}

// Round 19
// 17.501 us; speedup vs baseline: 1.0097x; 1.0097x over previous
//
#include <hip/hip_runtime.h>
#include <hip/hip_bf16.h>
#include <stdint.h>

// LogLinearCDE: out = softmax(W_out @ (y0 * prod_l flows[l]) + b_out)
// flows[l,h] = 1 + sum_c logsigs[l,c]*vf_A[c,h];  y0 = W_in@x0 + b_in
// R19 = R17 FINAL (best measured: 17.58 us, absmax 6.1e-5).
// TWO kernels, race-immune partial (single barrier, read-only LDS).
// partial: grid (16 colgroups x 16 rowsplits), 512 thr. Stage 1024 rows of A
// (36KB) + 256 cols of B (9KB) once -> ONE __syncthreads -> 32 row-tiles x
// 2 MFMAs (f16 main + k16 cleanup), fmaf product epilogue, y0 fold at rq==0.
// tail: ONE 1024-thread block, float4-resident, fixed-order logit reduction.
//
// Structural floor (ledger-measured): ~13 us fixed graph/dispatch overhead +
// ~4.5 us work. In-kernel global sync alternatives all cost more than a
// kernel boundary on MI355X: grid.sync +150us (R6), threadfence last-block
// +15us (R8), atomic-counter merge +7us (R12).

#define LSTEPS 16384
#define HID    4096
#define CC     17
#define NLAB   10
#define COLS   256              // cols per partial block
#define NCB    (HID/COLS)       // 16
#define RQ     16               // row splits
#define RPB    (LSTEPS/RQ)      // 1024 rows per block

typedef __attribute__((ext_vector_type(8)))  _Float16 half8;
typedef __attribute__((ext_vector_type(8)))  short short8;
typedef __attribute__((ext_vector_type(16))) float f32x16;

static __device__ __forceinline__ unsigned short f2h(float x) {
  _Float16 h = (_Float16)x;
  return *reinterpret_cast<unsigned short*>(&h);
}
static __device__ __forceinline__ uint32_t pk(unsigned short lo, unsigned short hi) {
  return (uint32_t)lo | ((uint32_t)hi << 16);
}
static __device__ __forceinline__ half8 frag_from_word(uint32_t w) {
  short8 s = {};
  s[0] = (short)(w & 0xffffu);
  s[1] = (short)(w >> 16);
  return __builtin_bit_cast(half8, s);
}

__global__ __launch_bounds__(512, 2) void partial_kernel(
    const float* __restrict__ logsigs, const float* __restrict__ vfA,
    const float* __restrict__ Win, const float* __restrict__ bin,
    const float* __restrict__ x0, float* __restrict__ ws_pp) {
  const int cb = blockIdx.x;    // 0..15 col group (256 cols)
  const int rq = blockIdx.y;    // 0..15 row split (1024 rows)
  const int tid = threadIdx.x;  // 512 threads

  __shared__ __align__(16) uint32_t sA[RPB][8];    // 32 KB  (k0-15 f16 pairs)
  __shared__ uint32_t sA4[RPB];                    //  4 KB  (k16)
  __shared__ __align__(16) uint32_t sB[2][COLS][4];//  8 KB
  __shared__ uint32_t sB4[COLS];                   //  1 KB

  // ---- stage B (tid < 256): col tid; k-loop coalesces across lanes
  if (tid < COLS) {
    const int gc = cb*COLS + tid;
    float v[CC];
    #pragma unroll
    for (int k = 0; k < CC; ++k) v[k] = vfA[(size_t)k*HID + gc];
    uint32_t w0[4], w1[4];
    #pragma unroll
    for (int j = 0; j < 4; ++j) {
      w0[j] = pk(f2h(v[2*j]),   f2h(v[2*j+1]));   // k0-7
      w1[j] = pk(f2h(v[8+2*j]), f2h(v[9+2*j]));   // k8-15
    }
    *reinterpret_cast<uint4*>(&sB[0][tid][0]) = make_uint4(w0[0],w0[1],w0[2],w0[3]);
    *reinterpret_cast<uint4*>(&sB[1][tid][0]) = make_uint4(w1[0],w1[1],w1[2],w1[3]);
    sB4[tid] = pk(f2h(v[16]), 0);
  }

  // ---- stage A: 1024 rows x 2 half-rows = 2048 tasks, 4 rounds of 512
  {
    const float* __restrict__ abase = logsigs + (size_t)rq*RPB*CC;
    #pragma unroll
    for (int rd = 0; rd < 4; ++rd) {
      const int e = rd*512 + tid;
      const int r = e >> 1, hf = e & 1;
      const float* __restrict__ row = abase + (size_t)r*CC + hf*8;
      uint32_t w[4];
      #pragma unroll
      for (int j = 0; j < 4; ++j) w[j] = pk(f2h(row[2*j]), f2h(row[2*j+1]));
      *reinterpret_cast<uint4*>(&sA[r][hf*4]) = make_uint4(w[0],w[1],w[2],w[3]);
      if (hf) sA4[r] = pk(f2h(row[8]), 0);
    }
  }
  __syncthreads();      // the ONLY barrier: LDS is read-only from here on

  const int lane = tid & 63, wv = tid >> 6;   // 8 waves
  const int cl = lane & 31, kh = lane >> 5;
  const int c = wv*32 + cl;                   // col within block

  const half8 Bm = __builtin_bit_cast(half8,
                     *reinterpret_cast<const short8*>(&sB[kh][c][0]));
  const half8 B4 = frag_from_word((kh == 0) ? sB4[c] : 0u);

  float p = 1.0f;
  #pragma unroll 4
  for (int it = 0; it < RPB/32; ++it) {       // 32 row-tiles
    const int rr = it*32 + cl;
    const half8 Am = __builtin_bit_cast(half8,
                       *reinterpret_cast<const short8*>(&sA[rr][kh*4]));
    const half8 A4 = frag_from_word((kh == 0) ? sA4[rr] : 0u);
    f32x16 a = {};
    a = __builtin_amdgcn_mfma_f32_32x32x16_f16(Am, Bm, a, 0, 0, 0);
    a = __builtin_amdgcn_mfma_f32_32x32x16_f16(A4, B4, a, 0, 0, 0);
    #pragma unroll
    for (int i = 0; i < 16; ++i) p = fmaf(a[i], p, p);   // p *= (1 + a[i])
  }
  // partner lane (^32) holds the other 16 rows of each 32-row tile
  p *= __shfl_xor(p, 32, 64);

  if (kh == 0) {
    const int gc = cb*COLS + c;
    float P = p;
    if (rq == 0) {              // fold y0 = W_in@x0 + b_in
      const float4* __restrict__ wrow =
          reinterpret_cast<const float4*>(Win + (size_t)gc*16);
      float y = bin[gc];
      #pragma unroll
      for (int q = 0; q < 4; ++q) {
        float4 w = wrow[q];
        y = fmaf(w.x, x0[4*q+0], y);
        y = fmaf(w.y, x0[4*q+1], y);
        y = fmaf(w.z, x0[4*q+2], y);
        y = fmaf(w.w, x0[4*q+3], y);
      }
      P *= y;
    }
    ws_pp[(size_t)rq*HID + gc] = P;
  }
}

// tail: ONE block, 1024 threads; thread owns 4 h (float4). No LDS staging.
__global__ __launch_bounds__(1024) void tail_kernel(
    const float* __restrict__ ws_pp, const float* __restrict__ Wout,
    const float* __restrict__ bout, float* __restrict__ out) {
  const int tid = threadIdx.x;
  __shared__ float sred[16][NLAB];
  __shared__ float slog[NLAB];

  const float4* __restrict__ pp4 = reinterpret_cast<const float4*>(ws_pp);
  float4 p = make_float4(1.0f, 1.0f, 1.0f, 1.0f);
  #pragma unroll
  for (int r = 0; r < RQ; ++r) {
    float4 v = pp4[(size_t)r*(HID/4) + tid];
    p.x *= v.x; p.y *= v.y; p.z *= v.z; p.w *= v.w;
  }

  const float4* __restrict__ wo4 = reinterpret_cast<const float4*>(Wout);
  float acc[NLAB];
  #pragma unroll
  for (int j = 0; j < NLAB; ++j) {
    float4 w = wo4[(size_t)j*(HID/4) + tid];
    acc[j] = w.x*p.x + w.y*p.y + w.z*p.z + w.w*p.w;
  }

  const int wv = tid >> 6, lane = tid & 63;
  #pragma unroll
  for (int j = 0; j < NLAB; ++j) {
    #pragma unroll
    for (int off = 1; off < 64; off <<= 1)
      acc[j] += __shfl_xor(acc[j], off, 64);
  }
  if (lane == 0) {
    #pragma unroll
    for (int j = 0; j < NLAB; ++j) sred[wv][j] = acc[j];
  }
  __syncthreads();
  if (tid < NLAB) {
    float s = bout[tid];
    #pragma unroll
    for (int w = 0; w < 16; ++w) s += sred[w][tid];
    slog[tid] = s;
  }
  __syncthreads();
  if (tid == 0) {
    float m = slog[0];
    #pragma unroll
    for (int j = 1; j < NLAB; ++j) m = fmaxf(m, slog[j]);
    float ssum = 0.0f;
    float e[NLAB];
    #pragma unroll
    for (int j = 0; j < NLAB; ++j) { e[j] = __expf(slog[j] - m); ssum += e[j]; }
    const float inv = 1.0f / ssum;
    #pragma unroll
    for (int j = 0; j < NLAB; ++j) out[j] = e[j] * inv;
  }
}

extern "C" void kernel_launch(void* const* d_in, const int* in_sizes, int n_in,
                              void* d_out, int out_size, void* d_ws, size_t ws_size,
                              hipStream_t stream) {
  // inputs: 0=ts (unused), 1=logsigs (L,C), 2=x0 (D), 3=W_in (H,D), 4=b_in (H),
  //         5=vf_A (C,H), 6=W_out (10,H), 7=b_out (10)
  const float* logsigs = (const float*)d_in[1];
  const float* x0      = (const float*)d_in[2];
  const float* Win     = (const float*)d_in[3];
  const float* bin     = (const float*)d_in[4];
  const float* vfA     = (const float*)d_in[5];
  const float* Wout    = (const float*)d_in[6];
  const float* bout    = (const float*)d_in[7];
  float* out = (float*)d_out;

  float* ws_pp = (float*)d_ws;     // RQ * HID f32 = 256 KB

  partial_kernel<<<dim3(NCB, RQ), 512, 0, stream>>>(logsigs, vfA, Win, bin, x0, ws_pp);
  tail_kernel<<<1, 1024, 0, stream>>>(ws_pp, Wout, bout, out);
}